// Round 1
// baseline (347.433 us; speedup 1.0000x reference)
//
#include <hip/hip_runtime.h>
#include <stdint.h>

#define DM 1024
#define NH 16
#define DEPTH 64
#define BB 2
#define NN 2048
#define ROWS (BB*NN)   // 4096

typedef __attribute__((ext_vector_type(8))) short short8;
typedef __attribute__((ext_vector_type(4))) short short4v;
typedef __attribute__((ext_vector_type(4))) float f32x4;

static __device__ __forceinline__ unsigned short f2b(float f) {
  unsigned u = __float_as_uint(f);
  u += 0x7fffu + ((u >> 16) & 1u);   // RNE
  return (unsigned short)(u >> 16);
}
static __device__ __forceinline__ float b2f(unsigned short u) {
  return __uint_as_float(((unsigned)u) << 16);
}

// ---------------- f32 -> bf16 convert (vec4) ----------------
__global__ void cvt_kernel(const float* __restrict__ src, unsigned short* __restrict__ dst, int n4) {
  int i = blockIdx.x * blockDim.x + threadIdx.x;
  int stride = gridDim.x * blockDim.x;
  for (; i < n4; i += stride) {
    float4 v = reinterpret_cast<const float4*>(src)[i];
    short4v o;
    o.x = (short)f2b(v.x); o.y = (short)f2b(v.y);
    o.z = (short)f2b(v.z); o.w = (short)f2b(v.w);
    reinterpret_cast<short4v*>(dst)[i] = o;
  }
}

// ---------------- bf16 GEMM: C[m][n] = sum_k A[m][k]*B[n][k] + bias[n] ----------------
// m97 structure: 128x128 tile, BK=32, 4 waves, global_load_lds width 16.
template<int OUTF32>
__global__ __launch_bounds__(256)
void gemm_bt(const unsigned short* __restrict__ A, const unsigned short* __restrict__ B,
             const float* __restrict__ bias0, const float* __restrict__ bias1,
             const float* __restrict__ bias2,
             float* __restrict__ Cf, unsigned short* __restrict__ Cb,
             int K, int N) {
  __shared__ unsigned short As[128 * 32];
  __shared__ unsigned short Bs[128 * 32];
  const int tid = threadIdx.x;
  const int lane = tid & 63;
  const int w = tid >> 6;
  const int wr = w >> 1, wc = w & 1;
  const int l15 = lane & 15, l4 = lane >> 4;
  const int m0 = blockIdx.y * 128, n0 = blockIdx.x * 128;
  f32x4 acc[4][4] = {};
  const int nkt = K >> 5;
  for (int kt = 0; kt < nkt; ++kt) {
    const int kbase = kt * 32;
#pragma unroll
    for (int i = 0; i < 2; ++i) {
      int c = tid + i * 256;
      int row = c >> 2, ko = (c & 3) * 8;
      __builtin_amdgcn_global_load_lds(
          (__attribute__((address_space(1))) void*)(A + (size_t)(m0 + row) * K + kbase + ko),
          (__attribute__((address_space(3))) void*)((char*)As + c * 16), 16, 0, 0);
      __builtin_amdgcn_global_load_lds(
          (__attribute__((address_space(1))) void*)(B + (size_t)(n0 + row) * K + kbase + ko),
          (__attribute__((address_space(3))) void*)((char*)Bs + c * 16), 16, 0, 0);
    }
    __syncthreads();
    short8 a[4], b[4];
#pragma unroll
    for (int mi = 0; mi < 4; ++mi)
      a[mi] = *reinterpret_cast<const short8*>(&As[(wr * 64 + mi * 16 + l15) * 32 + l4 * 8]);
#pragma unroll
    for (int ni = 0; ni < 4; ++ni)
      b[ni] = *reinterpret_cast<const short8*>(&Bs[(wc * 64 + ni * 16 + l15) * 32 + l4 * 8]);
#pragma unroll
    for (int mi = 0; mi < 4; ++mi)
#pragma unroll
      for (int ni = 0; ni < 4; ++ni)
        acc[mi][ni] = __builtin_amdgcn_mfma_f32_16x16x32_bf16(a[mi], b[ni], acc[mi][ni], 0, 0, 0);
    __syncthreads();
  }
  // epilogue: bias + store (C/D layout: row=(l>>4)*4+r, col=l&15)
  const float* bp = bias0; int boff = 0;
  if (n0 >= 2048)      { bp = bias2; boff = 2048; }
  else if (n0 >= 1024) { bp = bias1; boff = 1024; }
#pragma unroll
  for (int ni = 0; ni < 4; ++ni) {
    int col = n0 + wc * 64 + ni * 16 + l15;
    float bv = bp[col - boff];
#pragma unroll
    for (int mi = 0; mi < 4; ++mi) {
      f32x4 v = acc[mi][ni];
#pragma unroll
      for (int r = 0; r < 4; ++r) {
        int row = m0 + wr * 64 + mi * 16 + l4 * 4 + r;
        float outv = v[r] + bv;
        if (OUTF32) Cf[(size_t)row * N + col] = outv;
        else        Cb[(size_t)row * N + col] = f2b(outv);
      }
    }
  }
}

// ---------------- transpose V: QKV[:, 2048+h*64+d] -> Vt[(b*16+h)*64+d][n] ----------------
__global__ __launch_bounds__(256)
void vtrans_kernel(const unsigned short* __restrict__ qkv, unsigned short* __restrict__ vt) {
  const int bh = blockIdx.y, b = bh >> 4, h = bh & 15;
  const int n0 = blockIdx.x * 64;
  __shared__ unsigned short t[64][72];  // [d][n-local], padded
  const unsigned short* src = qkv + (size_t)(b * NN) * 3072 + 2048 + h * 64;
#pragma unroll
  for (int i = 0; i < 2; ++i) {
    int c = threadIdx.x + i * 256;
    int row = c >> 3, d0 = (c & 7) * 8;
    short8 v = *reinterpret_cast<const short8*>(src + (size_t)(n0 + row) * 3072 + d0);
#pragma unroll
    for (int j = 0; j < 8; ++j) t[d0 + j][row] = (unsigned short)v[j];
  }
  __syncthreads();
  unsigned short* dst = vt + ((size_t)(b * NH + h) * DEPTH) * NN + n0;
#pragma unroll
  for (int i = 0; i < 2; ++i) {
    int c = threadIdx.x + i * 256;
    int d = c >> 3, nn0 = (c & 7) * 8;
    short8 v;
#pragma unroll
    for (int j = 0; j < 8; ++j) v[j] = (short)t[d][nn0 + j];
    *reinterpret_cast<short8*>(dst + (size_t)d * NN + nn0) = v;
  }
}

// ---------------- flash attention (causal), 4 independent waves, 32 q-rows each ----------------
__global__ __launch_bounds__(256)
void attn_kernel(const unsigned short* __restrict__ qkv, const unsigned short* __restrict__ vt,
                 unsigned short* __restrict__ aout) {
  const int tid = threadIdx.x, lane = tid & 63, w = tid >> 6;
  const int l15 = lane & 15, l4 = lane >> 4;
  const int bh = blockIdx.y, b = bh >> 4, h = bh & 15;
  const int q0 = blockIdx.x * 128;
  const int qw = q0 + w * 32;
  const unsigned short* Qp  = qkv + (size_t)(b * NN) * 3072 + h * 64;
  const unsigned short* Kp  = Qp + 1024;
  const unsigned short* Vtp = vt + (size_t)(b * NH + h) * DEPTH * NN;
  __shared__ unsigned short plds[4][32 * 40];  // wave-private P tile, row stride 40 (bank spread)
  unsigned short* pw = plds[w];

  // Q hoisted to registers: A-frag layout, lane holds Q[qrow0 + (l&15)][kk*32 + 8*(l>>4)+j]
  short8 aq[2][2];
#pragma unroll
  for (int rb = 0; rb < 2; ++rb)
#pragma unroll
    for (int kk = 0; kk < 2; ++kk)
      aq[rb][kk] = *reinterpret_cast<const short8*>(
          Qp + (size_t)(qw + rb * 16 + l15) * 3072 + kk * 32 + l4 * 8);

  f32x4 o[2][4] = {};
  float mrow[2][4], lrow[2][4];
#pragma unroll
  for (int rb = 0; rb < 2; ++rb)
#pragma unroll
    for (int r = 0; r < 4; ++r) { mrow[rb][r] = -3.0e38f; lrow[rb][r] = 0.0f; }

  const int nkt = (q0 >> 5) + w + 1;  // causal: k-tiles up to the diagonal
  const float scale = 0.125f;         // 1/sqrt(64)
  for (int kt = 0; kt < nkt; ++kt) {
    const int k0 = kt * 32;
    short8 bkf[2][2];
#pragma unroll
    for (int cf = 0; cf < 2; ++cf)
#pragma unroll
      for (int kk = 0; kk < 2; ++kk)
        bkf[cf][kk] = *reinterpret_cast<const short8*>(
            Kp + (size_t)(k0 + cf * 16 + l15) * 3072 + kk * 32 + l4 * 8);
    f32x4 s[2][2];
#pragma unroll
    for (int rb = 0; rb < 2; ++rb)
#pragma unroll
      for (int cf = 0; cf < 2; ++cf) {
        f32x4 z = {};
        z = __builtin_amdgcn_mfma_f32_16x16x32_bf16(aq[rb][0], bkf[cf][0], z, 0, 0, 0);
        s[rb][cf] = __builtin_amdgcn_mfma_f32_16x16x32_bf16(aq[rb][1], bkf[cf][1], z, 0, 0, 0);
      }
    const bool diag = (kt == nkt - 1);
    float alpha[2][4];
#pragma unroll
    for (int rb = 0; rb < 2; ++rb) {
#pragma unroll
      for (int r = 0; r < 4; ++r) {
        float s0 = s[rb][0][r] * scale;
        float s1 = s[rb][1][r] * scale;
        if (diag) {
          int qa = qw + rb * 16 + l4 * 4 + r;
          if (k0 + l15 > qa)      s0 = -3.0e38f;
          if (k0 + 16 + l15 > qa) s1 = -3.0e38f;
        }
        float pm = fmaxf(s0, s1);
#pragma unroll
        for (int d = 1; d < 16; d <<= 1) pm = fmaxf(pm, __shfl_xor(pm, d));
        float mo = mrow[rb][r];
        float mn = fmaxf(mo, pm);
        float al = __expf(mo - mn);
        mrow[rb][r] = mn;
        alpha[rb][r] = al;
        float p0 = __expf(s0 - mn);
        float p1 = __expf(s1 - mn);
        unsigned short p0b = f2b(p0), p1b = f2b(p1);
        p0 = b2f(p0b); p1 = b2f(p1b);  // use bf16-rounded values in denominator too
        float ps = p0 + p1;
#pragma unroll
        for (int d = 1; d < 16; d <<= 1) ps += __shfl_xor(ps, d);
        lrow[rb][r] = lrow[rb][r] * al + ps;
        int prow = rb * 16 + l4 * 4 + r;
        pw[prow * 40 + l15]      = p0b;
        pw[prow * 40 + 16 + l15] = p1b;
      }
    }
    // rescale O
#pragma unroll
    for (int rb = 0; rb < 2; ++rb)
#pragma unroll
      for (int dn = 0; dn < 4; ++dn)
#pragma unroll
        for (int r = 0; r < 4; ++r) o[rb][dn][r] *= alpha[rb][r];
    // PV: A = P (from LDS), B = V via Vt rows (contiguous)
    short8 pa[2];
#pragma unroll
    for (int rb = 0; rb < 2; ++rb)
      pa[rb] = *reinterpret_cast<const short8*>(&pw[(rb * 16 + l15) * 40 + l4 * 8]);
    short8 bvf[4];
#pragma unroll
    for (int dn = 0; dn < 4; ++dn)
      bvf[dn] = *reinterpret_cast<const short8*>(
          Vtp + (size_t)(dn * 16 + l15) * NN + k0 + l4 * 8);
#pragma unroll
    for (int rb = 0; rb < 2; ++rb)
#pragma unroll
      for (int dn = 0; dn < 4; ++dn)
        o[rb][dn] = __builtin_amdgcn_mfma_f32_16x16x32_bf16(pa[rb], bvf[dn], o[rb][dn], 0, 0, 0);
  }
  // normalize + store bf16 to attn_out
#pragma unroll
  for (int rb = 0; rb < 2; ++rb) {
    float inv[4];
#pragma unroll
    for (int r = 0; r < 4; ++r) inv[r] = 1.0f / lrow[rb][r];
#pragma unroll
    for (int dn = 0; dn < 4; ++dn) {
#pragma unroll
      for (int r = 0; r < 4; ++r) {
        int row = b * NN + qw + rb * 16 + l4 * 4 + r;
        int col = h * 64 + dn * 16 + l15;
        aout[(size_t)row * DM + col] = f2b(o[rb][dn][r] * inv[r]);
      }
    }
  }
}

extern "C" void kernel_launch(void* const* d_in, const int* in_sizes, int n_in,
                              void* d_out, int out_size, void* d_ws, size_t ws_size,
                              hipStream_t stream) {
  const float* X  = (const float*)d_in[0];
  // d_in[1]: mask — causal by construction, handled analytically
  const float* Wq = (const float*)d_in[2];
  const float* bq = (const float*)d_in[3];
  const float* Wk = (const float*)d_in[4];
  const float* bk = (const float*)d_in[5];
  const float* Wv = (const float*)d_in[6];
  const float* bv = (const float*)d_in[7];
  const float* Wo = (const float*)d_in[8];
  const float* bo = (const float*)d_in[9];
  float* out = (float*)d_out;

  char* ws = (char*)d_ws;
  unsigned short* Xb     = (unsigned short*)(ws);                        // 4096x1024 bf16 (8MB)
  unsigned short* Wstack = (unsigned short*)(ws + 8ull  * 1024 * 1024);  // 3072x1024 (6MB)
  unsigned short* Wob    = (unsigned short*)(ws + 14ull * 1024 * 1024);  // 1024x1024 (2MB)
  unsigned short* QKV    = (unsigned short*)(ws + 16ull * 1024 * 1024);  // 4096x3072 (24MB)
  unsigned short* Vt     = (unsigned short*)(ws + 40ull * 1024 * 1024);  // 32x64x2048 (8MB)
  unsigned short* AOut   = (unsigned short*)(ws + 48ull * 1024 * 1024);  // 4096x1024 (8MB)

  cvt_kernel<<<1024, 256, 0, stream>>>(X, Xb, ROWS * DM / 4);
  cvt_kernel<<<512, 256, 0, stream>>>(Wq, Wstack,                   DM * DM / 4);
  cvt_kernel<<<512, 256, 0, stream>>>(Wk, Wstack + 1024 * 1024,     DM * DM / 4);
  cvt_kernel<<<512, 256, 0, stream>>>(Wv, Wstack + 2 * 1024 * 1024, DM * DM / 4);
  cvt_kernel<<<512, 256, 0, stream>>>(Wo, Wob,                      DM * DM / 4);

  // QKV = Xb @ Wstack^T + [bq|bk|bv]  -> bf16
  gemm_bt<0><<<dim3(24, 32), 256, 0, stream>>>(Xb, Wstack, bq, bk, bv, nullptr, QKV, DM, 3072);
  // Vt
  vtrans_kernel<<<dim3(32, 32), 256, 0, stream>>>(QKV, Vt);
  // attention
  attn_kernel<<<dim3(16, 32), 256, 0, stream>>>(QKV, Vt, AOut);
  // out = AOut @ Wo^T + bo -> f32
  gemm_bt<1><<<dim3(8, 32), 256, 0, stream>>>(AOut, Wob, bo, bo, bo, out, nullptr, DM, DM);
}

// Round 4
// 305.735 us; speedup vs baseline: 1.1364x; 1.1364x over previous
//
#include <hip/hip_runtime.h>
#include <stdint.h>

#define DM 1024
#define NH 16
#define DEPTH 64
#define BB 2
#define NN 2048
#define ROWS (BB*NN)   // 4096

typedef __attribute__((ext_vector_type(8))) short short8;
typedef __attribute__((ext_vector_type(4))) short short4v;
typedef __attribute__((ext_vector_type(4))) float f32x4;

static __device__ __forceinline__ unsigned short f2b(float f) {
  unsigned u = __float_as_uint(f);
  u += 0x7fffu + ((u >> 16) & 1u);   // RNE
  return (unsigned short)(u >> 16);
}

// ---------------- fused f32 -> bf16 convert, 5 segments ----------------
__global__ void cvt5_kernel(const float* __restrict__ s0, const float* __restrict__ s1,
                            const float* __restrict__ s2, const float* __restrict__ s3,
                            const float* __restrict__ s4,
                            unsigned short* __restrict__ d0, unsigned short* __restrict__ d1,
                            unsigned short* __restrict__ d2, unsigned short* __restrict__ d3,
                            unsigned short* __restrict__ d4) {
  const float* src; unsigned short* dst; int n4;
  const int seg = blockIdx.y;
  if (seg == 0)      { src = s0; dst = d0; n4 = ROWS * DM / 4; }
  else if (seg == 1) { src = s1; dst = d1; n4 = DM * DM / 4; }
  else if (seg == 2) { src = s2; dst = d2; n4 = DM * DM / 4; }
  else if (seg == 3) { src = s3; dst = d3; n4 = DM * DM / 4; }
  else               { src = s4; dst = d4; n4 = DM * DM / 4; }
  int i = blockIdx.x * blockDim.x + threadIdx.x;
  int stride = gridDim.x * blockDim.x;
  for (; i < n4; i += stride) {
    float4 v = reinterpret_cast<const float4*>(src)[i];
    short4v o;
    o.x = (short)f2b(v.x); o.y = (short)f2b(v.y);
    o.z = (short)f2b(v.z); o.w = (short)f2b(v.w);
    reinterpret_cast<short4v*>(dst)[i] = o;
  }
}

// ---------------- bf16 GEMM: C[m][n] = (sum_k A[m][k]*B[n][k] + bias[n]) * sc ----------------
// sc0 applied only to the n<1024 segment (Q pre-scaling by 1/sqrt(DEPTH)).
template<int OUTF32>
__global__ __launch_bounds__(256)
void gemm_bt(const unsigned short* __restrict__ A, const unsigned short* __restrict__ B,
             const float* __restrict__ bias0, const float* __restrict__ bias1,
             const float* __restrict__ bias2, float sc0,
             float* __restrict__ Cf, unsigned short* __restrict__ Cb,
             int K, int N) {
  __shared__ unsigned short As[128 * 32];
  __shared__ unsigned short Bs[128 * 32];
  const int tid = threadIdx.x;
  const int lane = tid & 63;
  const int w = tid >> 6;
  const int wr = w >> 1, wc = w & 1;
  const int l15 = lane & 15, l4 = lane >> 4;
  const int m0 = blockIdx.y * 128, n0 = blockIdx.x * 128;
  f32x4 acc[4][4] = {};
  const int nkt = K >> 5;
  for (int kt = 0; kt < nkt; ++kt) {
    const int kbase = kt * 32;
#pragma unroll
    for (int i = 0; i < 2; ++i) {
      int c = tid + i * 256;
      int row = c >> 2, ko = (c & 3) * 8;
      __builtin_amdgcn_global_load_lds(
          (__attribute__((address_space(1))) void*)(A + (size_t)(m0 + row) * K + kbase + ko),
          (__attribute__((address_space(3))) void*)((char*)As + c * 16), 16, 0, 0);
      __builtin_amdgcn_global_load_lds(
          (__attribute__((address_space(1))) void*)(B + (size_t)(n0 + row) * K + kbase + ko),
          (__attribute__((address_space(3))) void*)((char*)Bs + c * 16), 16, 0, 0);
    }
    __syncthreads();
    short8 a[4], b[4];
#pragma unroll
    for (int mi = 0; mi < 4; ++mi)
      a[mi] = *reinterpret_cast<const short8*>(&As[(wr * 64 + mi * 16 + l15) * 32 + l4 * 8]);
#pragma unroll
    for (int ni = 0; ni < 4; ++ni)
      b[ni] = *reinterpret_cast<const short8*>(&Bs[(wc * 64 + ni * 16 + l15) * 32 + l4 * 8]);
#pragma unroll
    for (int mi = 0; mi < 4; ++mi)
#pragma unroll
      for (int ni = 0; ni < 4; ++ni)
        acc[mi][ni] = __builtin_amdgcn_mfma_f32_16x16x32_bf16(a[mi], b[ni], acc[mi][ni], 0, 0, 0);
    __syncthreads();
  }
  const float* bp = bias0; int boff = 0;
  if (n0 >= 2048)      { bp = bias2; boff = 2048; }
  else if (n0 >= 1024) { bp = bias1; boff = 1024; }
  const float sc = (n0 < 1024) ? sc0 : 1.0f;
#pragma unroll
  for (int ni = 0; ni < 4; ++ni) {
    int col = n0 + wc * 64 + ni * 16 + l15;
    float bv = bp[col - boff];
#pragma unroll
    for (int mi = 0; mi < 4; ++mi) {
      f32x4 v = acc[mi][ni];
#pragma unroll
      for (int r = 0; r < 4; ++r) {
        int row = m0 + wr * 64 + mi * 16 + l4 * 4 + r;
        float outv = (v[r] + bv) * sc;
        if (OUTF32) Cf[(size_t)row * N + col] = outv;
        else        Cb[(size_t)row * N + col] = f2b(outv);
      }
    }
  }
}

// ---------------- transpose V: QKV[:, 2048+h*64+d] -> Vt[(b*16+h)*64+d][n] ----------------
__global__ __launch_bounds__(256)
void vtrans_kernel(const unsigned short* __restrict__ qkv, unsigned short* __restrict__ vt) {
  const int bh = blockIdx.y, b = bh >> 4, h = bh & 15;
  const int n0 = blockIdx.x * 64;
  __shared__ unsigned short t[64][72];
  const unsigned short* src = qkv + (size_t)(b * NN) * 3072 + 2048 + h * 64;
#pragma unroll
  for (int i = 0; i < 2; ++i) {
    int c = threadIdx.x + i * 256;
    int row = c >> 3, d0 = (c & 7) * 8;
    short8 v = *reinterpret_cast<const short8*>(src + (size_t)(n0 + row) * 3072 + d0);
#pragma unroll
    for (int j = 0; j < 8; ++j) t[d0 + j][row] = (unsigned short)v[j];
  }
  __syncthreads();
  unsigned short* dst = vt + ((size_t)(b * NH + h) * DEPTH) * NN + n0;
#pragma unroll
  for (int i = 0; i < 2; ++i) {
    int c = threadIdx.x + i * 256;
    int d = c >> 3, nn0 = (c & 7) * 8;
    short8 v;
#pragma unroll
    for (int j = 0; j < 8; ++j) v[j] = (short)t[d][nn0 + j];
    *reinterpret_cast<short8*>(dst + (size_t)d * NN + nn0) = v;
  }
}

// ---------------- flash attention (causal), swapped-operand softmax ----------------
// Each wave: mirrored 16-row q-tile pair (i, 127-i) sequentially -> exactly 65
// k-tile-visits per wave, perfectly balanced. lane: q-col = l15, k in regs.
__global__ __launch_bounds__(256)
void attn_kernel(const unsigned short* __restrict__ qkv, const unsigned short* __restrict__ vt,
                 unsigned short* __restrict__ aout) {
  const int tid = threadIdx.x, lane = tid & 63, w = tid >> 6;
  const int l15 = lane & 15, l4 = lane >> 4;
  const unsigned u = blockIdx.x * 4 + w;   // wave-task id [0,2048)
  const int bh = u >> 6;
  const int ii = u & 63;
  const int b = bh >> 4, h = bh & 15;
  const unsigned short* Qp  = qkv + (size_t)(b * NN) * 3072 + h * 64;   // pre-scaled by 1/8
  const unsigned short* Kp  = Qp + 1024;
  const unsigned short* Vtp = vt + (size_t)(b * NH + h) * DEPTH * NN;
  __shared__ unsigned short plds[4][16 * 40];   // wave-private P[q][k], stride 40
  unsigned short* pw = plds[w];

  for (int ip = 0; ip < 2; ++ip) {
    const int qt = ip ? (127 - ii) : ii;   // 16-row q-tile index
    const int qp0 = qt * 16;
    const int nkt = (qt >> 1) + 1;         // 32-wide k-tiles up to diagonal
    // Q as B-frag: lane holds Q[qp0+l15][kk*32 + l4*8 + j]
    short8 qf[2];
#pragma unroll
    for (int kk = 0; kk < 2; ++kk)
      qf[kk] = *reinterpret_cast<const short8*>(
          Qp + (size_t)(qp0 + l15) * 3072 + kk * 32 + l4 * 8);
    f32x4 o[4] = {};
    float m = -3.0e38f, l = 0.0f;
    // preload K tile 0 (A-frag: lane holds K[k0+cf*16+l15][kk*32+l4*8+j])
    short8 kf[2][2];
#pragma unroll
    for (int cf = 0; cf < 2; ++cf)
#pragma unroll
      for (int kk = 0; kk < 2; ++kk)
        kf[cf][kk] = *reinterpret_cast<const short8*>(
            Kp + (size_t)(cf * 16 + l15) * 3072 + kk * 32 + l4 * 8);

    for (int kt = 0; kt < nkt; ++kt) {
      const int k0 = kt * 32;
      // S^T = K * Q : D[row=k-local][col=q-local]
      f32x4 s[2];
#pragma unroll
      for (int cf = 0; cf < 2; ++cf) {
        f32x4 z = {};
        z = __builtin_amdgcn_mfma_f32_16x16x32_bf16(kf[cf][0], qf[0], z, 0, 0, 0);
        s[cf] = __builtin_amdgcn_mfma_f32_16x16x32_bf16(kf[cf][1], qf[1], z, 0, 0, 0);
      }
      // prefetch V (this tile) and K (next tile) — consumed after softmax
      short8 vf[4];
#pragma unroll
      for (int dn = 0; dn < 4; ++dn)
        vf[dn] = *reinterpret_cast<const short8*>(
            Vtp + (size_t)(dn * 16 + l15) * NN + k0 + l4 * 8);
      const int kn = (kt + 1 < nkt) ? k0 + 32 : k0;
#pragma unroll
      for (int cf = 0; cf < 2; ++cf)
#pragma unroll
        for (int kk = 0; kk < 2; ++kk)
          kf[cf][kk] = *reinterpret_cast<const short8*>(
              Kp + (size_t)(kn + cf * 16 + l15) * 3072 + kk * 32 + l4 * 8);
      // softmax: per lane, q-col = qp0+l15, 8 k-values in regs (k = cf*16 + l4*4 + r)
      float p[2][4];
      const bool diag = (kt == nkt - 1);
#pragma unroll
      for (int cf = 0; cf < 2; ++cf)
#pragma unroll
        for (int r = 0; r < 4; ++r) {
          float x = s[cf][r];
          if (diag && (k0 + cf * 16 + l4 * 4 + r > qp0 + l15)) x = -3.0e38f;
          p[cf][r] = x;
        }
      float pm = fmaxf(
          fmaxf(fmaxf(p[0][0], p[0][1]), fmaxf(p[0][2], p[0][3])),
          fmaxf(fmaxf(p[1][0], p[1][1]), fmaxf(p[1][2], p[1][3])));
      pm = fmaxf(pm, __shfl_xor(pm, 16));
      pm = fmaxf(pm, __shfl_xor(pm, 32));
      const float mn = fmaxf(m, pm);
      const float al = __expf(m - mn);
      m = mn;
      float ps = 0.0f;
#pragma unroll
      for (int cf = 0; cf < 2; ++cf)
#pragma unroll
        for (int r = 0; r < 4; ++r) {
          p[cf][r] = __expf(p[cf][r] - mn);
          ps += p[cf][r];
        }
      ps += __shfl_xor(ps, 16);
      ps += __shfl_xor(ps, 32);
      l = l * al + ps;
      // pack P to bf16 pairs, store P[q][k] (transposed write, ~2-way banks = free)
#pragma unroll
      for (int cf = 0; cf < 2; ++cf)
#pragma unroll
        for (int hh = 0; hh < 2; ++hh) {
          unsigned pk;
          asm("v_cvt_pk_bf16_f32 %0, %1, %2"
              : "=v"(pk) : "v"(p[cf][2 * hh]), "v"(p[cf][2 * hh + 1]));
          *reinterpret_cast<unsigned*>(&pw[l15 * 40 + cf * 16 + l4 * 4 + 2 * hh]) = pk;
        }
      // rescale O^T (per-lane scalar al)
#pragma unroll
      for (int dn = 0; dn < 4; ++dn)
#pragma unroll
        for (int r = 0; r < 4; ++r) o[dn][r] *= al;
      // O^T += V^T * P^T : A = Vt rows (d), B = P[q][k] rows
      short8 pf = *reinterpret_cast<const short8*>(&pw[l15 * 40 + l4 * 8]);
#pragma unroll
      for (int dn = 0; dn < 4; ++dn)
        o[dn] = __builtin_amdgcn_mfma_f32_16x16x32_bf16(vf[dn], pf, o[dn], 0, 0, 0);
    }
    // normalize + store: lane owns row q = qp0+l15, cols d = dn*16 + l4*4 + r
    const float inv = 1.0f / l;
    const int row = b * NN + qp0 + l15;
#pragma unroll
    for (int dn = 0; dn < 4; ++dn) {
      short4v ov;
#pragma unroll
      for (int r = 0; r < 4; ++r) ov[r] = (short)f2b(o[dn][r] * inv);
      *reinterpret_cast<short4v*>(&aout[(size_t)row * DM + h * 64 + dn * 16 + l4 * 4]) = ov;
    }
  }
}

extern "C" void kernel_launch(void* const* d_in, const int* in_sizes, int n_in,
                              void* d_out, int out_size, void* d_ws, size_t ws_size,
                              hipStream_t stream) {
  const float* X  = (const float*)d_in[0];
  // d_in[1]: mask — causal by construction, handled analytically
  const float* Wq = (const float*)d_in[2];
  const float* bq = (const float*)d_in[3];
  const float* Wk = (const float*)d_in[4];
  const float* bk = (const float*)d_in[5];
  const float* Wv = (const float*)d_in[6];
  const float* bv = (const float*)d_in[7];
  const float* Wo = (const float*)d_in[8];
  const float* bo = (const float*)d_in[9];
  float* out = (float*)d_out;

  char* ws = (char*)d_ws;
  unsigned short* Xb     = (unsigned short*)(ws);                        // 4096x1024 bf16 (8MB)
  unsigned short* Wstack = (unsigned short*)(ws + 8ull  * 1024 * 1024);  // 3072x1024 (6MB)
  unsigned short* Wob    = (unsigned short*)(ws + 14ull * 1024 * 1024);  // 1024x1024 (2MB)
  unsigned short* QKV    = (unsigned short*)(ws + 16ull * 1024 * 1024);  // 4096x3072 (24MB)
  unsigned short* Vt     = (unsigned short*)(ws + 40ull * 1024 * 1024);  // 32x64x2048 (8MB)
  unsigned short* AOut   = (unsigned short*)(ws + 48ull * 1024 * 1024);  // 4096x1024 (8MB)

  cvt5_kernel<<<dim3(128, 5), 256, 0, stream>>>(X, Wq, Wk, Wv, Wo,
                                                Xb, Wstack, Wstack + 1024 * 1024,
                                                Wstack + 2 * 1024 * 1024, Wob);

  // QKV = Xb @ Wstack^T + [bq|bk|bv]; Q segment pre-scaled by 1/8 -> bf16
  gemm_bt<0><<<dim3(24, 32), 256, 0, stream>>>(Xb, Wstack, bq, bk, bv, 0.125f,
                                               nullptr, QKV, DM, 3072);
  vtrans_kernel<<<dim3(32, 32), 256, 0, stream>>>(QKV, Vt);
  attn_kernel<<<dim3(512), 256, 0, stream>>>(QKV, Vt, AOut);
  // out = AOut @ Wo^T + bo -> f32
  gemm_bt<1><<<dim3(8, 32), 256, 0, stream>>>(AOut, Wob, bo, bo, bo, 1.0f,
                                              out, nullptr, DM, DM);
}